// Round 6
// baseline (1651.650 us; speedup 1.0000x reference)
//
#include <hip/hip_runtime.h>
#include <hip/hip_bf16.h>

#define EPSF 1e-5f

__device__ __forceinline__ float bf2f(unsigned short h) {
  unsigned int u = ((unsigned int)h) << 16;
  return __builtin_bit_cast(float, u);
}
__device__ __forceinline__ unsigned short f2bf(float f) {
  unsigned int u = __builtin_bit_cast(unsigned int, f);
  unsigned int r = (u + 0x7fffu + ((u >> 16) & 1u)) >> 16;
  return (unsigned short)r;
}
// dual-mode scalar read: f32 (mode=1) or bf16 (mode=0)
__device__ __forceinline__ float ldx(const void* p, size_t i, int f32m) {
  return f32m ? ((const float*)p)[i] : bf2f(((const unsigned short*)p)[i]);
}
struct F8 { float v[8]; };
__device__ __forceinline__ F8 ld8f(const void* p, size_t eoff, int f32m) {
  F8 r;
  if (f32m) {
    const float* q = (const float*)p + eoff;
    float4 a = ((const float4*)q)[0];
    float4 b = ((const float4*)q)[1];
    r.v[0]=a.x; r.v[1]=a.y; r.v[2]=a.z; r.v[3]=a.w;
    r.v[4]=b.x; r.v[5]=b.y; r.v[6]=b.z; r.v[7]=b.w;
  } else {
    uint4 u = *(const uint4*)((const unsigned short*)p + eoff);
    unsigned w[4] = {u.x, u.y, u.z, u.w};
#pragma unroll
    for (int i = 0; i < 4; i++) {
      r.v[2*i]   = __builtin_bit_cast(float, (w[i] & 0xffffu) << 16);
      r.v[2*i+1] = __builtin_bit_cast(float, w[i] & 0xffff0000u);
    }
  }
  return r;
}

// block-wide (256 thr) LDS tree sum of (x,y); s = float[512] scratch
__device__ __forceinline__ float2 bred2(float x, float y, float* s) {
  int t = threadIdx.x;
  s[t] = x; s[t + 256] = y;
  __syncthreads();
#pragma unroll
  for (int o = 128; o > 0; o >>= 1) {
    if (t < o) { s[t] += s[t + o]; s[t + 256] += s[t + 256 + o]; }
    __syncthreads();
  }
  float rx = s[0], ry = s[256];
  __syncthreads();
  return make_float2(rx, ry);
}

// ---- probes: flags[0]=1 if float inputs are f32 (not bf16);
//      flags[1]=1 if category is int64 (not int32)
__global__ void detect_mode(const unsigned short* rgb, const int* cat, int* flags) {
  __shared__ int c1s, c2s;
  if (threadIdx.x == 0) { c1s = 0; c2s = 0; }
  __syncthreads();
  int c1 = 0, c2 = 0;
  for (int i = threadIdx.x; i < 4096; i += 256) {
    unsigned e = (rgb[i] >> 7) & 0xFFu;
    if (e >= 0x90u) c1++;
  }
  for (int i = threadIdx.x; i < 1024; i += 256) {
    if (cat[2 * i + 1] != 0) c2++;   // int32: odd slots are cat values (~94% nz); int64: high words = 0
  }
  atomicAdd(&c1s, c1);
  atomicAdd(&c2s, c2);
  __syncthreads();
  if (threadIdx.x == 0) {
    flags[0] = (c1s > 64) ? 1 : 0;
    flags[1] = (c2s < 8) ? 1 : 0;
  }
}

// -------- VALU GEMM, natural-layout B: C[M,N] = A[M,K] @ B[K,N] --------------
// 64x64 tile, 256 thr, thread owns 4x4. B split at nsplit (rgb GEMM: [vW|qW]).
// A dual-mode if aDyn; B always dual-mode (raw harness weights). C out bf16.
__global__ __launch_bounds__(256) void gemm64n(
    const void* __restrict__ A, int lda,
    const void* __restrict__ B0, const void* __restrict__ B1,
    int ldbn, int nsplit,
    unsigned short* __restrict__ C, int ldc, int K,
    const int* __restrict__ flags, int aDyn) {
  __shared__ float As[64][33];
  __shared__ float Bs[32][65];
  int t = threadIdx.x;
  int mode = flags[0];
  int am = aDyn ? mode : 0;
  int m0 = blockIdx.x * 64, n0 = blockIdx.y * 64;
  const void* B = B0; int nb = n0;
  if (n0 >= nsplit) { B = B1; nb = n0 - nsplit; }
  int arow = t >> 2, acol = (t & 3) * 8;
  int brow = t >> 3, bcol = (t & 7) * 8;
  int tx = t & 15, ty = t >> 4;
  float acc[4][4];
#pragma unroll
  for (int i = 0; i < 4; i++)
#pragma unroll
    for (int j = 0; j < 4; j++) acc[i][j] = 0.f;
  for (int k0 = 0; k0 < K; k0 += 32) {
    F8 fa = ld8f(A, (size_t)(m0 + arow) * lda + k0 + acol, am);
    F8 fb = ld8f(B, (size_t)(k0 + brow) * ldbn + nb + bcol, mode);
#pragma unroll
    for (int j = 0; j < 8; j++) As[arow][acol + j] = fa.v[j];
#pragma unroll
    for (int j = 0; j < 8; j++) Bs[brow][bcol + j] = fb.v[j];
    __syncthreads();
    for (int kk = 0; kk < 32; kk++) {
      float a[4], b[4];
#pragma unroll
      for (int i = 0; i < 4; i++) a[i] = As[ty * 4 + i][kk];
#pragma unroll
      for (int j = 0; j < 4; j++) b[j] = Bs[kk][tx * 4 + j];
#pragma unroll
      for (int i = 0; i < 4; i++)
#pragma unroll
        for (int j = 0; j < 4; j++) acc[i][j] += a[i] * b[j];
    }
    __syncthreads();
  }
#pragma unroll
  for (int i = 0; i < 4; i++)
#pragma unroll
    for (int j = 0; j < 4; j++)
      C[(size_t)(m0 + ty * 4 + i) * ldc + (n0 + tx * 4 + j)] = f2bf(acc[i][j]);
}

// --------- heads: LN(rgb GEMM halves)+tanh + tiny low-obs path ---------------
__global__ __launch_bounds__(256) void ln_heads(
    const unsigned short* __restrict__ CF, const void* __restrict__ low,
    const void* __restrict__ vWlow, const void* __restrict__ qWlow,
    const void* __restrict__ vgr, const void* __restrict__ vbr,
    const void* __restrict__ qgr, const void* __restrict__ qbr,
    const void* __restrict__ vgl, const void* __restrict__ vbl,
    const void* __restrict__ qgl, const void* __restrict__ qbl,
    unsigned short* __restrict__ hv, unsigned short* __restrict__ hq,
    const int* __restrict__ flags) {
  __shared__ float lowf[32];
  __shared__ float red[512];
  int mode = flags[0];
  int b = blockIdx.x, j = threadIdx.x;
  if (j < 32) lowf[j] = ldx(low, (size_t)b * 32 + j, mode);
  __syncthreads();
  float xvr = bf2f(CF[(size_t)b * 512 + j]);
  float xqr = bf2f(CF[(size_t)b * 512 + 256 + j]);
  float xvl = 0.f, xql = 0.f;
#pragma unroll 4
  for (int k = 0; k < 32; k++) {
    float l = lowf[k];
    xvl += l * ldx(vWlow, k * 256 + j, mode);
    xql += l * ldx(qWlow, k * 256 + j, mode);
  }
  float2 r;
  r = bred2(xvr, xvr * xvr, red);
  {
    float mu = r.x * (1.f / 256.f), var = r.y * (1.f / 256.f) - mu * mu;
    float y = (xvr - mu) * rsqrtf(fmaxf(var, 0.f) + EPSF) * ldx(vgr, j, mode) + ldx(vbr, j, mode);
    hv[(size_t)b * 512 + j] = f2bf(tanhf(y));
  }
  r = bred2(xvl, xvl * xvl, red);
  {
    float mu = r.x * (1.f / 256.f), var = r.y * (1.f / 256.f) - mu * mu;
    float y = (xvl - mu) * rsqrtf(fmaxf(var, 0.f) + EPSF) * ldx(vgl, j, mode) + ldx(vbl, j, mode);
    hv[(size_t)b * 512 + 256 + j] = f2bf(tanhf(y));
  }
  r = bred2(xqr, xqr * xqr, red);
  {
    float mu = r.x * (1.f / 256.f), var = r.y * (1.f / 256.f) - mu * mu;
    float y = (xqr - mu) * rsqrtf(fmaxf(var, 0.f) + EPSF) * ldx(qgr, j, mode) + ldx(qbr, j, mode);
    hq[(size_t)b * 512 + j] = f2bf(tanhf(y));
  }
  r = bred2(xql, xql * xql, red);
  {
    float mu = r.x * (1.f / 256.f), var = r.y * (1.f / 256.f) - mu * mu;
    float y = (xql - mu) * rsqrtf(fmaxf(var, 0.f) + EPSF) * ldx(qgl, j, mode) + ldx(qbl, j, mode);
    hq[(size_t)b * 512 + 256 + j] = f2bf(tanhf(y));
  }
}

// ---------- LN(512)+silu; optional store (outh) and fused value head ---------
// valout is FLOAT32 (reference output dtype)
__global__ __launch_bounds__(256) void ln_silu(
    const unsigned short* __restrict__ CF, const void* __restrict__ g,
    const void* __restrict__ bb, unsigned short* __restrict__ outh,
    const void* __restrict__ Wh, const void* __restrict__ bh,
    float* __restrict__ valout, const int* __restrict__ flags) {
  __shared__ float red[512];
  int mode = flags[0];
  int b = blockIdx.x, j = threadIdx.x;
  float x0 = bf2f(CF[(size_t)b * 512 + j]);
  float x1 = bf2f(CF[(size_t)b * 512 + 256 + j]);
  float2 r = bred2(x0 + x1, x0 * x0 + x1 * x1, red);
  float mu = r.x * (1.f / 512.f);
  float var = r.y * (1.f / 512.f) - mu * mu;
  float rs = rsqrtf(fmaxf(var, 0.f) + EPSF);
  float y0 = (x0 - mu) * rs * ldx(g, j, mode) + ldx(bb, j, mode);
  float y1 = (x1 - mu) * rs * ldx(g, j + 256, mode) + ldx(bb, j + 256, mode);
  y0 = y0 / (1.f + expf(-y0));
  y1 = y1 / (1.f + expf(-y1));
  if (outh != nullptr) {
    outh[(size_t)b * 512 + j] = f2bf(y0);
    outh[(size_t)b * 512 + 256 + j] = f2bf(y1);
  }
  if (Wh != nullptr) {
    float p = y0 * ldx(Wh, j, mode) + y1 * ldx(Wh, j + 256, mode);
    float2 rv = bred2(p, 0.f, red);
    if (j == 0) valout[b] = rv.x + ldx(bh, 0, mode);
  }
}

// ---- hq1[(bl*24+s)*512+n] = silu(LN(base[bl,n] + act(b,s,:)·qW1[512+d][n]))
__global__ __launch_bounds__(256) void hq1_build(
    const unsigned short* __restrict__ Cbase, const int* __restrict__ cat, int b0,
    const void* __restrict__ qW1,
    const void* __restrict__ g1, const void* __restrict__ b1,
    unsigned short* __restrict__ hq1, const int* __restrict__ flags) {
  __shared__ float M[4][8];
  __shared__ float red[512];
  int mode = flags[0], w64 = flags[1];
  int b = blockIdx.x, j = threadIdx.x;
  if (j < 8) {
    size_t ci = (size_t)(b0 + b) * 24;
    int c0 = w64 ? cat[2 * (ci + j)]      : cat[ci + j];
    int c1 = w64 ? cat[2 * (ci + 8 + j)]  : cat[ci + 8 + j];
    int c2 = w64 ? cat[2 * (ci + 16 + j)] : cat[ci + 16 + j];
    float m1 = -1.f + (2.f * c0 + 1.f) * 0.0625f;
    float m2 = m1 - 0.0625f + (2.f * c1 + 1.f) * 0.00390625f;
    float m3 = m2 - 0.00390625f + (2.f * c2 + 1.f) * 0.000244140625f;
    M[0][j] = 0.f; M[1][j] = m1; M[2][j] = m2; M[3][j] = m3;
  }
  float xb0 = bf2f(Cbase[(size_t)b * 512 + j]);
  float xb1 = bf2f(Cbase[(size_t)b * 512 + 256 + j]);
  float aw0[8], aw1[8];
#pragma unroll
  for (int d = 0; d < 8; d++) {
    aw0[d] = ldx(qW1, (size_t)(512 + d) * 512 + j, mode);
    aw1[d] = ldx(qW1, (size_t)(512 + d) * 512 + 256 + j, mode);
  }
  float gg0 = ldx(g1, j, mode), bv0 = ldx(b1, j, mode);
  float gg1 = ldx(g1, j + 256, mode), bv1 = ldx(b1, j + 256, mode);
  __syncthreads();
  for (int s = 0; s < 24; s++) {
    int ls = s >> 3, ds = s & 7;
    float x0 = xb0, x1 = xb1;
#pragma unroll
    for (int d = 0; d < 8; d++) {
      float a = M[ls + ((d < ds) ? 1 : 0)][d];
      x0 += a * aw0[d];
      x1 += a * aw1[d];
    }
    float2 r = bred2(x0 + x1, x0 * x0 + x1 * x1, red);
    float mu = r.x * (1.f / 512.f);
    float var = r.y * (1.f / 512.f) - mu * mu;
    float rs = rsqrtf(fmaxf(var, 0.f) + EPSF);
    float y0 = (x0 - mu) * rs * gg0 + bv0;
    float y1 = (x1 - mu) * rs * gg1 + bv1;
    y0 = y0 / (1.f + expf(-y0));
    y1 = y1 / (1.f + expf(-y1));
    size_t o = ((size_t)b * 24 + s) * 512;
    hq1[o + j] = f2bf(y0);
    hq1[o + 256 + j] = f2bf(y1);
  }
}

// ---- adv head: LN(g2,b2)+silu on Cbig row, dot with qWh diag slice ----------
// outAdv is FLOAT32 (reference output dtype)
__global__ __launch_bounds__(256) void adv_head(
    const unsigned short* __restrict__ Cbig, const void* __restrict__ qWh,
    const void* __restrict__ qbh, const void* __restrict__ g2,
    const void* __restrict__ b2, float* __restrict__ outAdv,
    const int* __restrict__ flags) {
  __shared__ float whsf[512 * 16];
  __shared__ float hbuf[512];
  __shared__ float part[256];
  __shared__ float red[512];
  int mode = flags[0];
  int s = blockIdx.x, j = threadIdx.x;
  for (int idx = j; idx < 8192; idx += 256) {
    int n = idx >> 4, c = idx & 15;
    whsf[idx] = ldx(qWh, (size_t)n * 384 + s * 16 + c, mode);
  }
  float gg0 = ldx(g2, j, mode), bb0 = ldx(b2, j, mode);
  float gg1 = ldx(g2, j + 256, mode), bb1 = ldx(b2, j + 256, mode);
  float qb = (j < 16) ? ldx(qbh, s * 16 + j, mode) : 0.f;
  __syncthreads();
  int bin = j & 15, chunk = j >> 4;
  for (int i = 0; i < 8; i++) {
    int b = blockIdx.y * 8 + i;
    size_t ro = ((size_t)b * 24 + s) * 512;
    float x0 = bf2f(Cbig[ro + j]);
    float x1 = bf2f(Cbig[ro + 256 + j]);
    float2 r = bred2(x0 + x1, x0 * x0 + x1 * x1, red);
    float mu = r.x * (1.f / 512.f);
    float var = r.y * (1.f / 512.f) - mu * mu;
    float rs = rsqrtf(fmaxf(var, 0.f) + EPSF);
    float y0 = (x0 - mu) * rs * gg0 + bb0;
    float y1 = (x1 - mu) * rs * gg1 + bb1;
    y0 = y0 / (1.f + expf(-y0));
    y1 = y1 / (1.f + expf(-y1));
    hbuf[j] = y0;
    hbuf[j + 256] = y1;
    __syncthreads();
    float p = 0.f;
#pragma unroll 8
    for (int ii = 0; ii < 32; ii++) {
      int n = chunk + 16 * ii;
      p += hbuf[n] * whsf[n * 16 + bin];
    }
    part[j] = p;
    __syncthreads();
    if (j < 16) {
      float acc = qb;
#pragma unroll
      for (int c = 0; c < 16; c++) acc += part[j + 16 * c];
      outAdv[(size_t)b * 384 + s * 16 + j] = acc;
    }
    __syncthreads();
  }
}

extern "C" void kernel_launch(void* const* d_in, const int* in_sizes, int n_in,
                              void* d_out, int out_size, void* d_ws, size_t ws_size,
                              hipStream_t stream) {
  const void* rgb = d_in[0];
  const void* low = d_in[1];
  const int*  cat = (const int*)d_in[2];
  float* out = (float*)d_out;   // reference output dtype is float32
  char* ws = (char*)d_ws;

  // ---- minimal ws layout (bytes): total need = 6.7 MB at Bc=8 ----
  int*            FLAGS = (int*)(ws + 0);                     // 4 KB
  unsigned short* CF    = (unsigned short*)(ws + 4096);       // 2048x512 bf16, 2 MB
  unsigned short* HVT1  = (unsigned short*)(ws + 2101248);    // 2 MB (HV then T1)
  unsigned short* HQ    = (unsigned short*)(ws + 4198400);    // 2 MB
  unsigned short* HQ1   = (unsigned short*)(ws + 6295552);    // Bc*24*512 bf16

  static const int bcs[7] = {512, 256, 128, 64, 32, 16, 8};
  int Bc = 8;  // best-effort floor
  for (int i = 0; i < 7; i++) {
    if (6295552 + (size_t)bcs[i] * 49152 <= ws_size) { Bc = bcs[i]; break; }
  }
  int nc = 2048 / Bc;
  unsigned short* CBIG = HQ1 + (size_t)Bc * 24 * 512;

  detect_mode<<<1, 256, 0, stream>>>((const unsigned short*)rgb, cat, FLAGS);

  const int BIG = 1 << 30;
  // rgb GEMM: CF = rgb @ [v_W_rgb | q_W_rgb]  (B natural (8192,256) each)
  gemm64n<<<dim3(32, 8), 256, 0, stream>>>(rgb, 8192, d_in[3], d_in[17], 256, 256,
                                           CF, 512, 8192, FLAGS, 1);
  ln_heads<<<2048, 256, 0, stream>>>(CF, low, d_in[6], d_in[20],
                                     d_in[4], d_in[5], d_in[18], d_in[19],
                                     d_in[7], d_in[8], d_in[21], d_in[22],
                                     HVT1, HQ, FLAGS);
  // value path (B natural (512,512))
  gemm64n<<<dim3(32, 8), 256, 0, stream>>>(HVT1, 512, d_in[9], d_in[9], 512, BIG,
                                           CF, 512, 512, FLAGS, 0);
  ln_silu<<<2048, 256, 0, stream>>>(CF, d_in[10], d_in[11], HVT1, nullptr, nullptr,
                                    nullptr, FLAGS);
  gemm64n<<<dim3(32, 8), 256, 0, stream>>>(HVT1, 512, d_in[12], d_in[12], 512, BIG,
                                           CF, 512, 512, FLAGS, 0);
  ln_silu<<<2048, 256, 0, stream>>>(CF, d_in[13], d_in[14], nullptr, d_in[15], d_in[16],
                                    out, FLAGS);
  // q path: base = HQ @ q_W1[0:512,:]  (q_W1 natural (520,512), row stride 512)
  gemm64n<<<dim3(32, 8), 256, 0, stream>>>(HQ, 512, d_in[23], d_in[23], 512, BIG,
                                           CF, 512, 512, FLAGS, 0);
  for (int c = 0; c < nc; c++) {
    int b0 = c * Bc;
    hq1_build<<<Bc, 256, 0, stream>>>(CF + (size_t)b0 * 512, cat, b0, d_in[23],
                                      d_in[24], d_in[25], HQ1, FLAGS);
    gemm64n<<<dim3(Bc * 24 / 64, 8), 256, 0, stream>>>(HQ1, 512, d_in[26], d_in[26],
                                                       512, BIG, CBIG, 512, 512, FLAGS, 0);
    adv_head<<<dim3(24, Bc / 8), 256, 0, stream>>>(CBIG, d_in[29], d_in[30],
                                                   d_in[27], d_in[28],
                                                   out + 2048 + (size_t)b0 * 384, FLAGS);
  }
}

// Round 7
// 879.214 us; speedup vs baseline: 1.8786x; 1.8786x over previous
//
#include <hip/hip_runtime.h>
#include <hip/hip_bf16.h>

#define EPSF 1e-5f

typedef __bf16 bf16x8 __attribute__((ext_vector_type(8)));
typedef float f32x4 __attribute__((ext_vector_type(4)));
typedef short svec8 __attribute__((ext_vector_type(8)));
typedef short svec4 __attribute__((ext_vector_type(4)));

__device__ __forceinline__ float bf2f(unsigned short h) {
  unsigned int u = ((unsigned int)h) << 16;
  return __builtin_bit_cast(float, u);
}
__device__ __forceinline__ unsigned short f2bf(float f) {
  unsigned int u = __builtin_bit_cast(unsigned int, f);
  unsigned int r = (u + 0x7fffu + ((u >> 16) & 1u)) >> 16;
  return (unsigned short)r;
}
// dual-mode scalar read: f32 (mode=1) or bf16 (mode=0)
__device__ __forceinline__ float ldx(const void* p, size_t i, int f32m) {
  return f32m ? ((const float*)p)[i] : bf2f(((const unsigned short*)p)[i]);
}
// dual-mode 8-element load -> 8 bf16 (svec8)
__device__ __forceinline__ svec8 ld8bf(const void* p, size_t eoff, int f32m) {
  if (!f32m) {
    uint4 u = *(const uint4*)((const unsigned short*)p + eoff);
    return __builtin_bit_cast(svec8, u);
  }
  const float* q = (const float*)p + eoff;
  float4 a = ((const float4*)q)[0];
  float4 b = ((const float4*)q)[1];
  svec8 r;
  r[0] = (short)f2bf(a.x); r[1] = (short)f2bf(a.y);
  r[2] = (short)f2bf(a.z); r[3] = (short)f2bf(a.w);
  r[4] = (short)f2bf(b.x); r[5] = (short)f2bf(b.y);
  r[6] = (short)f2bf(b.z); r[7] = (short)f2bf(b.w);
  return r;
}

// block-wide (256 thr) sum of (x,y) via wave shuffles; s = float[16] scratch
__device__ __forceinline__ float2 bred2(float x, float y, float* s) {
#pragma unroll
  for (int o = 32; o > 0; o >>= 1) {
    x += __shfl_xor(x, o, 64);
    y += __shfl_xor(y, o, 64);
  }
  int w = threadIdx.x >> 6;
  if ((threadIdx.x & 63) == 0) { s[w] = x; s[8 + w] = y; }
  __syncthreads();
  float rx = s[0] + s[1] + s[2] + s[3];
  float ry = s[8] + s[9] + s[10] + s[11];
  __syncthreads();
  return make_float2(rx, ry);
}

// ---- probes: flags[0]=1 if float inputs are f32; flags[1]=1 if cat is int64
__global__ void detect_mode(const unsigned short* rgb, const int* cat, int* flags) {
  __shared__ int c1s, c2s;
  if (threadIdx.x == 0) { c1s = 0; c2s = 0; }
  __syncthreads();
  int c1 = 0, c2 = 0;
  for (int i = threadIdx.x; i < 4096; i += 256) {
    unsigned e = (rgb[i] >> 7) & 0xFFu;
    if (e >= 0x90u) c1++;
  }
  for (int i = threadIdx.x; i < 1024; i += 256) {
    if (cat[2 * i + 1] != 0) c2++;
  }
  atomicAdd(&c1s, c1);
  atomicAdd(&c2s, c2);
  __syncthreads();
  if (threadIdx.x == 0) {
    flags[0] = (c1s > 64) ? 1 : 0;
    flags[1] = (c2s < 8) ? 1 : 0;
  }
}

// -------- MFMA GEMM, natural-layout B: C[M,N] = A[M,K] @ B[K,N] --------------
// 64x64 tile, 256 thr = 4 waves; wave w covers cols w*16..w*16+15.
// A-frags: ds_read_b128 from As (stride 40, 2-way free). B staged natural
// (Bs[k][n], stride 68): b-frag = 8 strided ds_read_u16 (2-way free banks).
// Engine core verified bit-identical vs VALU oracle in R3/R4.
__global__ __launch_bounds__(256) void gemm64m(
    const void* __restrict__ A, int lda,
    const void* __restrict__ B0, const void* __restrict__ B1,
    int ldbn, int nsplit,
    unsigned short* __restrict__ C, int ldc, int K,
    const int* __restrict__ flags, int aDyn) {
  __shared__ __align__(16) unsigned short As[64 * 40];
  __shared__ __align__(16) unsigned short Bs[32 * 68];
  int t = threadIdx.x;
  int mode = flags[0], am = aDyn ? mode : 0;
  int wave = t >> 6, lane = t & 63, mr = lane & 15, q = lane >> 4;
  int m0 = blockIdx.x * 64, n0 = blockIdx.y * 64;
  const void* B = B0; int nb = n0;
  if (n0 >= nsplit) { B = B1; nb = n0 - nsplit; }
  int arow = t >> 2, acol = (t & 3) * 8;   // A-tile 64m x 32k
  int brow = t >> 3, bcol = (t & 7) * 8;   // B-tile 32k x 64n
  size_t abase = (size_t)(m0 + arow) * lda + acol;
  size_t bbase = (size_t)brow * ldbn + nb + bcol;
  f32x4 acc[4];
#pragma unroll
  for (int i = 0; i < 4; i++) acc[i] = (f32x4){0.f, 0.f, 0.f, 0.f};
  svec8 ra = ld8bf(A, abase, am);
  svec8 rb = ld8bf(B, bbase, mode);
  int aw = arow * 40 + acol;
  int bw = brow * 68 + bcol;
  for (int k0 = 0; k0 < K; k0 += 32) {
    *(svec8*)&As[aw] = ra;
    *(svec4*)&Bs[bw]     = __builtin_shufflevector(rb, rb, 0, 1, 2, 3);
    *(svec4*)&Bs[bw + 4] = __builtin_shufflevector(rb, rb, 4, 5, 6, 7);
    __syncthreads();
    if (k0 + 32 < K) {  // register prefetch of next K-tile
      ra = ld8bf(A, abase + k0 + 32, am);
      rb = ld8bf(B, bbase + (size_t)(k0 + 32) * ldbn, mode);
    }
    svec8 bsv;
#pragma unroll
    for (int j = 0; j < 8; j++)
      bsv[j] = (short)Bs[(q * 8 + j) * 68 + wave * 16 + mr];
    bf16x8 bfr = __builtin_bit_cast(bf16x8, bsv);
#pragma unroll
    for (int i = 0; i < 4; i++) {
      bf16x8 afr = *(const bf16x8*)(const void*)&As[(i * 16 + mr) * 40 + q * 8];
      acc[i] = __builtin_amdgcn_mfma_f32_16x16x32_bf16(afr, bfr, acc[i], 0, 0, 0);
    }
    __syncthreads();
  }
  int n = n0 + wave * 16 + mr;
#pragma unroll
  for (int i = 0; i < 4; i++)
#pragma unroll
    for (int r = 0; r < 4; r++)
      C[(size_t)(m0 + i * 16 + q * 4 + r) * ldc + n] = f2bf(acc[i][r]);
}

// --------- heads: LN(rgb GEMM halves)+tanh + tiny low-obs path ---------------
__global__ __launch_bounds__(256) void ln_heads(
    const unsigned short* __restrict__ CF, const void* __restrict__ low,
    const void* __restrict__ vWlow, const void* __restrict__ qWlow,
    const void* __restrict__ vgr, const void* __restrict__ vbr,
    const void* __restrict__ qgr, const void* __restrict__ qbr,
    const void* __restrict__ vgl, const void* __restrict__ vbl,
    const void* __restrict__ qgl, const void* __restrict__ qbl,
    unsigned short* __restrict__ hv, unsigned short* __restrict__ hq,
    const int* __restrict__ flags) {
  __shared__ float lowf[32];
  __shared__ float red[16];
  int mode = flags[0];
  int b = blockIdx.x, j = threadIdx.x;
  if (j < 32) lowf[j] = ldx(low, (size_t)b * 32 + j, mode);
  __syncthreads();
  float xvr = bf2f(CF[(size_t)b * 512 + j]);
  float xqr = bf2f(CF[(size_t)b * 512 + 256 + j]);
  float xvl = 0.f, xql = 0.f;
#pragma unroll 4
  for (int k = 0; k < 32; k++) {
    float l = lowf[k];
    xvl += l * ldx(vWlow, k * 256 + j, mode);
    xql += l * ldx(qWlow, k * 256 + j, mode);
  }
  float2 r;
  r = bred2(xvr, xvr * xvr, red);
  {
    float mu = r.x * (1.f / 256.f), var = r.y * (1.f / 256.f) - mu * mu;
    float y = (xvr - mu) * rsqrtf(fmaxf(var, 0.f) + EPSF) * ldx(vgr, j, mode) + ldx(vbr, j, mode);
    hv[(size_t)b * 512 + j] = f2bf(tanhf(y));
  }
  r = bred2(xvl, xvl * xvl, red);
  {
    float mu = r.x * (1.f / 256.f), var = r.y * (1.f / 256.f) - mu * mu;
    float y = (xvl - mu) * rsqrtf(fmaxf(var, 0.f) + EPSF) * ldx(vgl, j, mode) + ldx(vbl, j, mode);
    hv[(size_t)b * 512 + 256 + j] = f2bf(tanhf(y));
  }
  r = bred2(xqr, xqr * xqr, red);
  {
    float mu = r.x * (1.f / 256.f), var = r.y * (1.f / 256.f) - mu * mu;
    float y = (xqr - mu) * rsqrtf(fmaxf(var, 0.f) + EPSF) * ldx(qgr, j, mode) + ldx(qbr, j, mode);
    hq[(size_t)b * 512 + j] = f2bf(tanhf(y));
  }
  r = bred2(xql, xql * xql, red);
  {
    float mu = r.x * (1.f / 256.f), var = r.y * (1.f / 256.f) - mu * mu;
    float y = (xql - mu) * rsqrtf(fmaxf(var, 0.f) + EPSF) * ldx(qgl, j, mode) + ldx(qbl, j, mode);
    hq[(size_t)b * 512 + 256 + j] = f2bf(tanhf(y));
  }
}

// ---------- LN(512)+silu; optional store (outh) and fused value head ---------
__global__ __launch_bounds__(256) void ln_silu(
    const unsigned short* __restrict__ CF, const void* __restrict__ g,
    const void* __restrict__ bb, unsigned short* __restrict__ outh,
    const void* __restrict__ Wh, const void* __restrict__ bh,
    float* __restrict__ valout, const int* __restrict__ flags) {
  __shared__ float red[16];
  int mode = flags[0];
  int b = blockIdx.x, j = threadIdx.x;
  float x0 = bf2f(CF[(size_t)b * 512 + j]);
  float x1 = bf2f(CF[(size_t)b * 512 + 256 + j]);
  float2 r = bred2(x0 + x1, x0 * x0 + x1 * x1, red);
  float mu = r.x * (1.f / 512.f);
  float var = r.y * (1.f / 512.f) - mu * mu;
  float rs = rsqrtf(fmaxf(var, 0.f) + EPSF);
  float y0 = (x0 - mu) * rs * ldx(g, j, mode) + ldx(bb, j, mode);
  float y1 = (x1 - mu) * rs * ldx(g, j + 256, mode) + ldx(bb, j + 256, mode);
  y0 = y0 / (1.f + expf(-y0));
  y1 = y1 / (1.f + expf(-y1));
  if (outh != nullptr) {
    outh[(size_t)b * 512 + j] = f2bf(y0);
    outh[(size_t)b * 512 + 256 + j] = f2bf(y1);
  }
  if (Wh != nullptr) {
    float p = y0 * ldx(Wh, j, mode) + y1 * ldx(Wh, j + 256, mode);
    float2 rv = bred2(p, 0.f, red);
    if (j == 0) valout[b] = rv.x + ldx(bh, 0, mode);
  }
}

// ---- hq1[(bl*24+s)*512+n] = silu(LN(base[bl,n] + act(b,s,:)·qW1[512+d][n]))
__global__ __launch_bounds__(256) void hq1_build(
    const unsigned short* __restrict__ Cbase, const int* __restrict__ cat, int b0,
    const void* __restrict__ qW1,
    const void* __restrict__ g1, const void* __restrict__ b1,
    unsigned short* __restrict__ hq1, const int* __restrict__ flags) {
  __shared__ float M[4][8];
  __shared__ float red[16];
  int mode = flags[0], w64 = flags[1];
  int b = blockIdx.x, j = threadIdx.x;
  if (j < 8) {
    size_t ci = (size_t)(b0 + b) * 24;
    int c0 = w64 ? cat[2 * (ci + j)]      : cat[ci + j];
    int c1 = w64 ? cat[2 * (ci + 8 + j)]  : cat[ci + 8 + j];
    int c2 = w64 ? cat[2 * (ci + 16 + j)] : cat[ci + 16 + j];
    float m1 = -1.f + (2.f * c0 + 1.f) * 0.0625f;
    float m2 = m1 - 0.0625f + (2.f * c1 + 1.f) * 0.00390625f;
    float m3 = m2 - 0.00390625f + (2.f * c2 + 1.f) * 0.000244140625f;
    M[0][j] = 0.f; M[1][j] = m1; M[2][j] = m2; M[3][j] = m3;
  }
  float xb0 = bf2f(Cbase[(size_t)b * 512 + j]);
  float xb1 = bf2f(Cbase[(size_t)b * 512 + 256 + j]);
  float aw0[8], aw1[8];
#pragma unroll
  for (int d = 0; d < 8; d++) {
    aw0[d] = ldx(qW1, (size_t)(512 + d) * 512 + j, mode);
    aw1[d] = ldx(qW1, (size_t)(512 + d) * 512 + 256 + j, mode);
  }
  float gg0 = ldx(g1, j, mode), bv0 = ldx(b1, j, mode);
  float gg1 = ldx(g1, j + 256, mode), bv1 = ldx(b1, j + 256, mode);
  __syncthreads();
  for (int s = 0; s < 24; s++) {
    int ls = s >> 3, ds = s & 7;
    float x0 = xb0, x1 = xb1;
#pragma unroll
    for (int d = 0; d < 8; d++) {
      float a = M[ls + ((d < ds) ? 1 : 0)][d];
      x0 += a * aw0[d];
      x1 += a * aw1[d];
    }
    float2 r = bred2(x0 + x1, x0 * x0 + x1 * x1, red);
    float mu = r.x * (1.f / 512.f);
    float var = r.y * (1.f / 512.f) - mu * mu;
    float rs = rsqrtf(fmaxf(var, 0.f) + EPSF);
    float y0 = (x0 - mu) * rs * gg0 + bv0;
    float y1 = (x1 - mu) * rs * gg1 + bv1;
    y0 = y0 / (1.f + expf(-y0));
    y1 = y1 / (1.f + expf(-y1));
    size_t o = ((size_t)b * 24 + s) * 512;
    hq1[o + j] = f2bf(y0);
    hq1[o + 256 + j] = f2bf(y1);
  }
}

// ---- adv head: LN(g2,b2)+silu on Cbig row, dot with qWh diag slice ----------
__global__ __launch_bounds__(256) void adv_head(
    const unsigned short* __restrict__ Cbig, const void* __restrict__ qWh,
    const void* __restrict__ qbh, const void* __restrict__ g2,
    const void* __restrict__ b2, float* __restrict__ outAdv,
    const int* __restrict__ flags) {
  __shared__ float whsf[512 * 16];
  __shared__ float hbuf[512];
  __shared__ float part[256];
  __shared__ float red[16];
  int mode = flags[0];
  int s = blockIdx.x, j = threadIdx.x;
  for (int idx = j; idx < 8192; idx += 256) {
    int n = idx >> 4, c = idx & 15;
    whsf[idx] = ldx(qWh, (size_t)n * 384 + s * 16 + c, mode);
  }
  float gg0 = ldx(g2, j, mode), bb0 = ldx(b2, j, mode);
  float gg1 = ldx(g2, j + 256, mode), bb1 = ldx(b2, j + 256, mode);
  float qb = (j < 16) ? ldx(qbh, s * 16 + j, mode) : 0.f;
  __syncthreads();
  int bin = j & 15, chunk = j >> 4;
  for (int i = 0; i < 8; i++) {
    int b = blockIdx.y * 8 + i;
    size_t ro = ((size_t)b * 24 + s) * 512;
    float x0 = bf2f(Cbig[ro + j]);
    float x1 = bf2f(Cbig[ro + 256 + j]);
    float2 r = bred2(x0 + x1, x0 * x0 + x1 * x1, red);
    float mu = r.x * (1.f / 512.f);
    float var = r.y * (1.f / 512.f) - mu * mu;
    float rs = rsqrtf(fmaxf(var, 0.f) + EPSF);
    float y0 = (x0 - mu) * rs * gg0 + bb0;
    float y1 = (x1 - mu) * rs * gg1 + bb1;
    y0 = y0 / (1.f + expf(-y0));
    y1 = y1 / (1.f + expf(-y1));
    hbuf[j] = y0;
    hbuf[j + 256] = y1;
    __syncthreads();
    float p = 0.f;
#pragma unroll 8
    for (int ii = 0; ii < 32; ii++) {
      int n = chunk + 16 * ii;
      p += hbuf[n] * whsf[n * 16 + bin];
    }
    part[j] = p;
    __syncthreads();
    if (j < 16) {
      float acc = qb;
#pragma unroll
      for (int c = 0; c < 16; c++) acc += part[j + 16 * c];
      outAdv[(size_t)b * 384 + s * 16 + j] = acc;
    }
    __syncthreads();
  }
}

extern "C" void kernel_launch(void* const* d_in, const int* in_sizes, int n_in,
                              void* d_out, int out_size, void* d_ws, size_t ws_size,
                              hipStream_t stream) {
  const void* rgb = d_in[0];
  const void* low = d_in[1];
  const int*  cat = (const int*)d_in[2];
  float* out = (float*)d_out;   // reference output dtype is float32
  char* ws = (char*)d_ws;

  // ---- minimal ws layout (bytes): total need = 6.7 MB at Bc=8 ----
  int*            FLAGS = (int*)(ws + 0);                     // 4 KB
  unsigned short* CF    = (unsigned short*)(ws + 4096);       // 2048x512 bf16, 2 MB
  unsigned short* HVT1  = (unsigned short*)(ws + 2101248);    // 2 MB (HV then T1)
  unsigned short* HQ    = (unsigned short*)(ws + 4198400);    // 2 MB
  unsigned short* HQ1   = (unsigned short*)(ws + 6295552);    // Bc*24*512 bf16

  static const int bcs[7] = {512, 256, 128, 64, 32, 16, 8};
  int Bc = 8;  // best-effort floor
  for (int i = 0; i < 7; i++) {
    if (6295552 + (size_t)bcs[i] * 49152 <= ws_size) { Bc = bcs[i]; break; }
  }
  int nc = 2048 / Bc;
  unsigned short* CBIG = HQ1 + (size_t)Bc * 24 * 512;

  detect_mode<<<1, 256, 0, stream>>>((const unsigned short*)rgb, cat, FLAGS);

  const int BIG = 1 << 30;
  // rgb GEMM: CF = rgb @ [v_W_rgb | q_W_rgb]  (B natural (8192,256) each)
  gemm64m<<<dim3(32, 8), 256, 0, stream>>>(rgb, 8192, d_in[3], d_in[17], 256, 256,
                                           CF, 512, 8192, FLAGS, 1);
  ln_heads<<<2048, 256, 0, stream>>>(CF, low, d_in[6], d_in[20],
                                     d_in[4], d_in[5], d_in[18], d_in[19],
                                     d_in[7], d_in[8], d_in[21], d_in[22],
                                     HVT1, HQ, FLAGS);
  // value path (B natural (512,512))
  gemm64m<<<dim3(32, 8), 256, 0, stream>>>(HVT1, 512, d_in[9], d_in[9], 512, BIG,
                                           CF, 512, 512, FLAGS, 0);
  ln_silu<<<2048, 256, 0, stream>>>(CF, d_in[10], d_in[11], HVT1, nullptr, nullptr,
                                    nullptr, FLAGS);
  gemm64m<<<dim3(32, 8), 256, 0, stream>>>(HVT1, 512, d_in[12], d_in[12], 512, BIG,
                                           CF, 512, 512, FLAGS, 0);
  ln_silu<<<2048, 256, 0, stream>>>(CF, d_in[13], d_in[14], nullptr, d_in[15], d_in[16],
                                    out, FLAGS);
  // q path: base = HQ @ q_W1[0:512,:]  (q_W1 natural (520,512), row stride 512)
  gemm64m<<<dim3(32, 8), 256, 0, stream>>>(HQ, 512, d_in[23], d_in[23], 512, BIG,
                                           CF, 512, 512, FLAGS, 0);
  for (int c = 0; c < nc; c++) {
    int b0 = c * Bc;
    hq1_build<<<Bc, 256, 0, stream>>>(CF + (size_t)b0 * 512, cat, b0, d_in[23],
                                      d_in[24], d_in[25], HQ1, FLAGS);
    gemm64m<<<dim3(Bc * 24 / 64, 8), 256, 0, stream>>>(HQ1, 512, d_in[26], d_in[26],
                                                       512, BIG, CBIG, 512, 512, FLAGS, 0);
    adv_head<<<dim3(24, Bc / 8), 256, 0, stream>>>(CBIG, d_in[29], d_in[30],
                                                   d_in[27], d_in[28],
                                                   out + 2048 + (size_t)b0 * 384, FLAGS);
  }
}

// Round 8
// 668.563 us; speedup vs baseline: 2.4704x; 1.3151x over previous
//
#include <hip/hip_runtime.h>
#include <hip/hip_bf16.h>

#define EPSF 1e-5f

typedef __bf16 bf16x8 __attribute__((ext_vector_type(8)));
typedef float f32x4 __attribute__((ext_vector_type(4)));
typedef short svec8 __attribute__((ext_vector_type(8)));
typedef short svec4 __attribute__((ext_vector_type(4)));

__device__ __forceinline__ float bf2f(unsigned short h) {
  unsigned int u = ((unsigned int)h) << 16;
  return __builtin_bit_cast(float, u);
}
__device__ __forceinline__ unsigned short f2bf(float f) {
  unsigned int u = __builtin_bit_cast(unsigned int, f);
  unsigned int r = (u + 0x7fffu + ((u >> 16) & 1u)) >> 16;
  return (unsigned short)r;
}
// dual-mode scalar read: f32 (mode=1) or bf16 (mode=0)
__device__ __forceinline__ float ldx(const void* p, size_t i, int f32m) {
  return f32m ? ((const float*)p)[i] : bf2f(((const unsigned short*)p)[i]);
}
// dual-mode 8-element load -> 8 bf16 (svec8)
__device__ __forceinline__ svec8 ld8bf(const void* p, size_t eoff, int f32m) {
  if (!f32m) {
    uint4 u = *(const uint4*)((const unsigned short*)p + eoff);
    return __builtin_bit_cast(svec8, u);
  }
  const float* q = (const float*)p + eoff;
  float4 a = ((const float4*)q)[0];
  float4 b = ((const float4*)q)[1];
  svec8 r;
  r[0] = (short)f2bf(a.x); r[1] = (short)f2bf(a.y);
  r[2] = (short)f2bf(a.z); r[3] = (short)f2bf(a.w);
  r[4] = (short)f2bf(b.x); r[5] = (short)f2bf(b.y);
  r[6] = (short)f2bf(b.z); r[7] = (short)f2bf(b.w);
  return r;
}

// block-wide (256 thr) sum of (x,y) via wave shuffles; s = float[16] scratch
__device__ __forceinline__ float2 bred2(float x, float y, float* s) {
#pragma unroll
  for (int o = 32; o > 0; o >>= 1) {
    x += __shfl_xor(x, o, 64);
    y += __shfl_xor(y, o, 64);
  }
  int w = threadIdx.x >> 6;
  if ((threadIdx.x & 63) == 0) { s[w] = x; s[8 + w] = y; }
  __syncthreads();
  float rx = s[0] + s[1] + s[2] + s[3];
  float ry = s[8] + s[9] + s[10] + s[11];
  __syncthreads();
  return make_float2(rx, ry);
}

// ---- probes: flags[0]=1 if float inputs are f32; flags[1]=1 if cat is int64
__global__ void detect_mode(const unsigned short* rgb, const int* cat, int* flags) {
  __shared__ int c1s, c2s;
  if (threadIdx.x == 0) { c1s = 0; c2s = 0; }
  __syncthreads();
  int c1 = 0, c2 = 0;
  for (int i = threadIdx.x; i < 4096; i += 256) {
    unsigned e = (rgb[i] >> 7) & 0xFFu;
    if (e >= 0x90u) c1++;
  }
  for (int i = threadIdx.x; i < 1024; i += 256) {
    if (cat[2 * i + 1] != 0) c2++;
  }
  atomicAdd(&c1s, c1);
  atomicAdd(&c2s, c2);
  __syncthreads();
  if (threadIdx.x == 0) {
    flags[0] = (c1s > 64) ? 1 : 0;
    flags[1] = (c2s < 8) ? 1 : 0;
  }
}

// ---- zero an f32 buffer (graph-safe, re-run every launch) -------------------
__global__ void zerof(float* p, int n4) {
  int i = blockIdx.x * 256 + threadIdx.x;
  if (i < n4) ((float4*)p)[i] = make_float4(0.f, 0.f, 0.f, 0.f);
}

// -------- MFMA GEMM, natural-layout B: C[M,N] = A[M,K] @ B[K,N] --------------
// 64x64 tile, 256 thr = 4 waves. Split-K via grid.z (kslice per z-block).
// outKind: 0 = f32 store, 1 = f32 atomicAdd (split-K), 2 = bf16 store.
__global__ __launch_bounds__(256) void gemm64m(
    const void* __restrict__ A, int lda,
    const void* __restrict__ B0, const void* __restrict__ B1,
    int ldbn, int nsplit,
    void* __restrict__ Cv, int ldc, int kslice,
    const int* __restrict__ flags, int aDyn, int outKind) {
  __shared__ __align__(16) unsigned short As[64 * 40];
  __shared__ __align__(16) unsigned short Bs[32 * 68];
  int t = threadIdx.x;
  int mode = flags[0], am = aDyn ? mode : 0;
  int wave = t >> 6, lane = t & 63, mr = lane & 15, q = lane >> 4;
  int m0 = blockIdx.x * 64, n0 = blockIdx.y * 64;
  int kbeg = blockIdx.z * kslice;
  const void* B = B0; int nb = n0;
  if (n0 >= nsplit) { B = B1; nb = n0 - nsplit; }
  int arow = t >> 2, acol = (t & 3) * 8;   // A-tile 64m x 32k
  int brow = t >> 3, bcol = (t & 7) * 8;   // B-tile 32k x 64n
  size_t abase = (size_t)(m0 + arow) * lda + kbeg + acol;
  size_t bbase = (size_t)(kbeg + brow) * ldbn + nb + bcol;
  f32x4 acc[4];
#pragma unroll
  for (int i = 0; i < 4; i++) acc[i] = (f32x4){0.f, 0.f, 0.f, 0.f};
  svec8 ra = ld8bf(A, abase, am);
  svec8 rb = ld8bf(B, bbase, mode);
  int aw = arow * 40 + acol;
  int bw = brow * 68 + bcol;
  for (int k0 = 0; k0 < kslice; k0 += 32) {
    *(svec8*)&As[aw] = ra;
    *(svec4*)&Bs[bw]     = __builtin_shufflevector(rb, rb, 0, 1, 2, 3);
    *(svec4*)&Bs[bw + 4] = __builtin_shufflevector(rb, rb, 4, 5, 6, 7);
    __syncthreads();
    if (k0 + 32 < kslice) {  // register prefetch of next K-tile
      ra = ld8bf(A, abase + k0 + 32, am);
      rb = ld8bf(B, bbase + (size_t)(k0 + 32) * ldbn, mode);
    }
    svec8 bsv;
#pragma unroll
    for (int j = 0; j < 8; j++)
      bsv[j] = (short)Bs[(q * 8 + j) * 68 + wave * 16 + mr];
    bf16x8 bfr = __builtin_bit_cast(bf16x8, bsv);
#pragma unroll
    for (int i = 0; i < 4; i++) {
      bf16x8 afr = *(const bf16x8*)(const void*)&As[(i * 16 + mr) * 40 + q * 8];
      acc[i] = __builtin_amdgcn_mfma_f32_16x16x32_bf16(afr, bfr, acc[i], 0, 0, 0);
    }
    __syncthreads();
  }
  int n = n0 + wave * 16 + mr;
  if (outKind == 2) {
    unsigned short* C = (unsigned short*)Cv;
#pragma unroll
    for (int i = 0; i < 4; i++)
#pragma unroll
      for (int r = 0; r < 4; r++)
        C[(size_t)(m0 + i * 16 + q * 4 + r) * ldc + n] = f2bf(acc[i][r]);
  } else if (outKind == 0) {
    float* C = (float*)Cv;
#pragma unroll
    for (int i = 0; i < 4; i++)
#pragma unroll
      for (int r = 0; r < 4; r++)
        C[(size_t)(m0 + i * 16 + q * 4 + r) * ldc + n] = acc[i][r];
  } else {
    float* C = (float*)Cv;
#pragma unroll
    for (int i = 0; i < 4; i++)
#pragma unroll
      for (int r = 0; r < 4; r++)
        atomicAdd(&C[(size_t)(m0 + i * 16 + q * 4 + r) * ldc + n], acc[i][r]);
  }
}

// --------- heads: LN(rgb GEMM halves)+tanh + tiny low-obs path ---------------
__global__ __launch_bounds__(256) void ln_heads(
    const float* __restrict__ CF, const void* __restrict__ low,
    const void* __restrict__ vWlow, const void* __restrict__ qWlow,
    const void* __restrict__ vgr, const void* __restrict__ vbr,
    const void* __restrict__ qgr, const void* __restrict__ qbr,
    const void* __restrict__ vgl, const void* __restrict__ vbl,
    const void* __restrict__ qgl, const void* __restrict__ qbl,
    unsigned short* __restrict__ hv, unsigned short* __restrict__ hq,
    const int* __restrict__ flags) {
  __shared__ float lowf[32];
  __shared__ float red[16];
  int mode = flags[0];
  int b = blockIdx.x, j = threadIdx.x;
  if (j < 32) lowf[j] = ldx(low, (size_t)b * 32 + j, mode);
  __syncthreads();
  float xvr = CF[(size_t)b * 512 + j];
  float xqr = CF[(size_t)b * 512 + 256 + j];
  float xvl = 0.f, xql = 0.f;
#pragma unroll 4
  for (int k = 0; k < 32; k++) {
    float l = lowf[k];
    xvl += l * ldx(vWlow, k * 256 + j, mode);
    xql += l * ldx(qWlow, k * 256 + j, mode);
  }
  float2 r;
  r = bred2(xvr, xvr * xvr, red);
  {
    float mu = r.x * (1.f / 256.f), var = r.y * (1.f / 256.f) - mu * mu;
    float y = (xvr - mu) * rsqrtf(fmaxf(var, 0.f) + EPSF) * ldx(vgr, j, mode) + ldx(vbr, j, mode);
    hv[(size_t)b * 512 + j] = f2bf(tanhf(y));
  }
  r = bred2(xvl, xvl * xvl, red);
  {
    float mu = r.x * (1.f / 256.f), var = r.y * (1.f / 256.f) - mu * mu;
    float y = (xvl - mu) * rsqrtf(fmaxf(var, 0.f) + EPSF) * ldx(vgl, j, mode) + ldx(vbl, j, mode);
    hv[(size_t)b * 512 + 256 + j] = f2bf(tanhf(y));
  }
  r = bred2(xqr, xqr * xqr, red);
  {
    float mu = r.x * (1.f / 256.f), var = r.y * (1.f / 256.f) - mu * mu;
    float y = (xqr - mu) * rsqrtf(fmaxf(var, 0.f) + EPSF) * ldx(qgr, j, mode) + ldx(qbr, j, mode);
    hq[(size_t)b * 512 + j] = f2bf(tanhf(y));
  }
  r = bred2(xql, xql * xql, red);
  {
    float mu = r.x * (1.f / 256.f), var = r.y * (1.f / 256.f) - mu * mu;
    float y = (xql - mu) * rsqrtf(fmaxf(var, 0.f) + EPSF) * ldx(qgl, j, mode) + ldx(qbl, j, mode);
    hq[(size_t)b * 512 + 256 + j] = f2bf(tanhf(y));
  }
}

// ---------- LN(512)+silu; optional store (outh) and fused value head ---------
__global__ __launch_bounds__(256) void ln_silu(
    const float* __restrict__ CF, const void* __restrict__ g,
    const void* __restrict__ bb, unsigned short* __restrict__ outh,
    const void* __restrict__ Wh, const void* __restrict__ bh,
    float* __restrict__ valout, const int* __restrict__ flags) {
  __shared__ float red[16];
  int mode = flags[0];
  int b = blockIdx.x, j = threadIdx.x;
  float x0 = CF[(size_t)b * 512 + j];
  float x1 = CF[(size_t)b * 512 + 256 + j];
  float2 r = bred2(x0 + x1, x0 * x0 + x1 * x1, red);
  float mu = r.x * (1.f / 512.f);
  float var = r.y * (1.f / 512.f) - mu * mu;
  float rs = rsqrtf(fmaxf(var, 0.f) + EPSF);
  float y0 = (x0 - mu) * rs * ldx(g, j, mode) + ldx(bb, j, mode);
  float y1 = (x1 - mu) * rs * ldx(g, j + 256, mode) + ldx(bb, j + 256, mode);
  y0 = y0 / (1.f + expf(-y0));
  y1 = y1 / (1.f + expf(-y1));
  if (outh != nullptr) {
    outh[(size_t)b * 512 + j] = f2bf(y0);
    outh[(size_t)b * 512 + 256 + j] = f2bf(y1);
  }
  if (Wh != nullptr) {
    float p = y0 * ldx(Wh, j, mode) + y1 * ldx(Wh, j + 256, mode);
    float2 rv = bred2(p, 0.f, red);
    if (j == 0) valout[b] = rv.x + ldx(bh, 0, mode);
  }
}

// ---- hq1[(bl*24+s)*512+n] = silu(LN(base[bl,n] + act(b,s,:)·qW1[512+d][n]))
__global__ __launch_bounds__(256) void hq1_build(
    const float* __restrict__ Cbase, const int* __restrict__ cat, int b0,
    const void* __restrict__ qW1,
    const void* __restrict__ g1, const void* __restrict__ b1,
    unsigned short* __restrict__ hq1, const int* __restrict__ flags) {
  __shared__ float M[4][8];
  __shared__ float red[16];
  int mode = flags[0], w64 = flags[1];
  int b = blockIdx.x, j = threadIdx.x;
  if (j < 8) {
    size_t ci = (size_t)(b0 + b) * 24;
    int c0 = w64 ? cat[2 * (ci + j)]      : cat[ci + j];
    int c1 = w64 ? cat[2 * (ci + 8 + j)]  : cat[ci + 8 + j];
    int c2 = w64 ? cat[2 * (ci + 16 + j)] : cat[ci + 16 + j];
    float m1 = -1.f + (2.f * c0 + 1.f) * 0.0625f;
    float m2 = m1 - 0.0625f + (2.f * c1 + 1.f) * 0.00390625f;
    float m3 = m2 - 0.00390625f + (2.f * c2 + 1.f) * 0.000244140625f;
    M[0][j] = 0.f; M[1][j] = m1; M[2][j] = m2; M[3][j] = m3;
  }
  float xb0 = Cbase[(size_t)b * 512 + j];
  float xb1 = Cbase[(size_t)b * 512 + 256 + j];
  float aw0[8], aw1[8];
#pragma unroll
  for (int d = 0; d < 8; d++) {
    aw0[d] = ldx(qW1, (size_t)(512 + d) * 512 + j, mode);
    aw1[d] = ldx(qW1, (size_t)(512 + d) * 512 + 256 + j, mode);
  }
  float gg0 = ldx(g1, j, mode), bv0 = ldx(b1, j, mode);
  float gg1 = ldx(g1, j + 256, mode), bv1 = ldx(b1, j + 256, mode);
  __syncthreads();
  for (int s = 0; s < 24; s++) {
    int ls = s >> 3, ds = s & 7;
    float x0 = xb0, x1 = xb1;
#pragma unroll
    for (int d = 0; d < 8; d++) {
      float a = M[ls + ((d < ds) ? 1 : 0)][d];
      x0 += a * aw0[d];
      x1 += a * aw1[d];
    }
    float2 r = bred2(x0 + x1, x0 * x0 + x1 * x1, red);
    float mu = r.x * (1.f / 512.f);
    float var = r.y * (1.f / 512.f) - mu * mu;
    float rs = rsqrtf(fmaxf(var, 0.f) + EPSF);
    float y0 = (x0 - mu) * rs * gg0 + bv0;
    float y1 = (x1 - mu) * rs * gg1 + bv1;
    y0 = y0 / (1.f + expf(-y0));
    y1 = y1 / (1.f + expf(-y1));
    size_t o = ((size_t)b * 24 + s) * 512;
    hq1[o + j] = f2bf(y0);
    hq1[o + 256 + j] = f2bf(y1);
  }
}

// ---- adv head: LN(g2,b2)+silu on Cbig row, dot with qWh diag slice ----------
__global__ __launch_bounds__(256) void adv_head(
    const unsigned short* __restrict__ Cbig, const void* __restrict__ qWh,
    const void* __restrict__ qbh, const void* __restrict__ g2,
    const void* __restrict__ b2, float* __restrict__ outAdv,
    const int* __restrict__ flags) {
  __shared__ float whsf[512 * 16];
  __shared__ float hbuf[512];
  __shared__ float part[256];
  __shared__ float red[16];
  int mode = flags[0];
  int s = blockIdx.x, j = threadIdx.x;
  for (int idx = j; idx < 8192; idx += 256) {
    int n = idx >> 4, c = idx & 15;
    whsf[idx] = ldx(qWh, (size_t)n * 384 + s * 16 + c, mode);
  }
  float gg0 = ldx(g2, j, mode), bb0 = ldx(b2, j, mode);
  float gg1 = ldx(g2, j + 256, mode), bb1 = ldx(b2, j + 256, mode);
  float qb = (j < 16) ? ldx(qbh, s * 16 + j, mode) : 0.f;
  __syncthreads();
  int bin = j & 15, chunk = j >> 4;
  for (int i = 0; i < 8; i++) {
    int b = blockIdx.y * 8 + i;
    size_t ro = ((size_t)b * 24 + s) * 512;
    float x0 = bf2f(Cbig[ro + j]);
    float x1 = bf2f(Cbig[ro + 256 + j]);
    float2 r = bred2(x0 + x1, x0 * x0 + x1 * x1, red);
    float mu = r.x * (1.f / 512.f);
    float var = r.y * (1.f / 512.f) - mu * mu;
    float rs = rsqrtf(fmaxf(var, 0.f) + EPSF);
    float y0 = (x0 - mu) * rs * gg0 + bb0;
    float y1 = (x1 - mu) * rs * gg1 + bb1;
    y0 = y0 / (1.f + expf(-y0));
    y1 = y1 / (1.f + expf(-y1));
    hbuf[j] = y0;
    hbuf[j + 256] = y1;
    __syncthreads();
    float p = 0.f;
#pragma unroll 8
    for (int ii = 0; ii < 32; ii++) {
      int n = chunk + 16 * ii;
      p += hbuf[n] * whsf[n * 16 + bin];
    }
    part[j] = p;
    __syncthreads();
    if (j < 16) {
      float acc = qb;
#pragma unroll
      for (int c = 0; c < 16; c++) acc += part[j + 16 * c];
      outAdv[(size_t)b * 384 + s * 16 + j] = acc;
    }
    __syncthreads();
  }
}

extern "C" void kernel_launch(void* const* d_in, const int* in_sizes, int n_in,
                              void* d_out, int out_size, void* d_ws, size_t ws_size,
                              hipStream_t stream) {
  const void* rgb = d_in[0];
  const void* low = d_in[1];
  const int*  cat = (const int*)d_in[2];
  float* out = (float*)d_out;   // reference output dtype is float32
  char* ws = (char*)d_ws;

  // ---- ws layout (bytes): min need ~8.8 MB at Bc=8 ----
  int*            FLAGS = (int*)(ws + 0);                     // 4 KB
  float*          CF    = (float*)(ws + 4096);                // 2048x512 f32, 4 MB
  unsigned short* HVT1  = (unsigned short*)(ws + 4198400);    // 2 MB (HV then T1)
  unsigned short* HQ    = (unsigned short*)(ws + 6295552);    // 2 MB
  unsigned short* HQ1   = (unsigned short*)(ws + 8392704);    // Bc*24*512 bf16

  static const int bcs[7] = {512, 256, 128, 64, 32, 16, 8};
  int Bc = 8;  // best-effort floor
  for (int i = 0; i < 7; i++) {
    if (8392704 + (size_t)bcs[i] * 49152 <= ws_size) { Bc = bcs[i]; break; }
  }
  int nc = 2048 / Bc;
  unsigned short* CBIG = HQ1 + (size_t)Bc * 24 * 512;

  detect_mode<<<1, 256, 0, stream>>>((const unsigned short*)rgb, cat, FLAGS);

  const int BIG = 1 << 30;
  // rgb GEMM, split-K=8: CF += rgb @ [v_W_rgb | q_W_rgb] (2048 blocks, 8/CU)
  zerof<<<1024, 256, 0, stream>>>(CF, 262144);
  gemm64m<<<dim3(32, 8, 8), 256, 0, stream>>>(rgb, 8192, d_in[3], d_in[17], 256, 256,
                                              CF, 512, 1024, FLAGS, 1, 1);
  ln_heads<<<2048, 256, 0, stream>>>(CF, low, d_in[6], d_in[20],
                                     d_in[4], d_in[5], d_in[18], d_in[19],
                                     d_in[7], d_in[8], d_in[21], d_in[22],
                                     HVT1, HQ, FLAGS);
  // value path (B natural (512,512)), direct f32 store
  gemm64m<<<dim3(32, 8, 1), 256, 0, stream>>>(HVT1, 512, d_in[9], d_in[9], 512, BIG,
                                              CF, 512, 512, FLAGS, 0, 0);
  ln_silu<<<2048, 256, 0, stream>>>(CF, d_in[10], d_in[11], HVT1, nullptr, nullptr,
                                    nullptr, FLAGS);
  gemm64m<<<dim3(32, 8, 1), 256, 0, stream>>>(HVT1, 512, d_in[12], d_in[12], 512, BIG,
                                              CF, 512, 512, FLAGS, 0, 0);
  ln_silu<<<2048, 256, 0, stream>>>(CF, d_in[13], d_in[14], nullptr, d_in[15], d_in[16],
                                    out, FLAGS);
  // q path: base = HQ @ q_W1[0:512,:]  (natural (520,512), row stride 512)
  gemm64m<<<dim3(32, 8, 1), 256, 0, stream>>>(HQ, 512, d_in[23], d_in[23], 512, BIG,
                                              CF, 512, 512, FLAGS, 0, 0);
  for (int c = 0; c < nc; c++) {
    int b0 = c * Bc;
    hq1_build<<<Bc, 256, 0, stream>>>(CF + (size_t)b0 * 512, cat, b0, d_in[23],
                                      d_in[24], d_in[25], HQ1, FLAGS);
    gemm64m<<<dim3(Bc * 24 / 64, 8, 1), 256, 0, stream>>>(HQ1, 512, d_in[26], d_in[26],
                                                          512, BIG, CBIG, 512, 512, FLAGS, 0, 2);
    adv_head<<<dim3(24, Bc / 8), 256, 0, stream>>>(CBIG, d_in[29], d_in[30],
                                                   d_in[27], d_in[28],
                                                   out + 2048 + (size_t)b0 * 384, FLAGS);
  }
}